// Round 1
// baseline (1048.296 us; speedup 1.0000x reference)
//
#include <hip/hip_runtime.h>
#include <hip/hip_bf16.h>

// Binary conv: out = conv2d(x, sign(w)), SAME, stride 1, NHWC.
// x: (32,112,112,128) f32, w: (3,3,128,256) f32, out: (32,112,112,256) f32.
// Implicit GEMM on bf16 MFMA: M=N*H*W tiles of 8x16 pixels, N=oc tiles of 128,
// K=(kh,kw,ic)=1152 in chunks of 32.

#define TH 8
#define TW 16
#define PH 10          // TH + 2 halo
#define PW 18          // TW + 2 halo
#define APIX (PH * PW) // 180 pixels
#define ASTRIDE 136    // 128 ic + 8 pad (bank shift of 4 per pixel -> conflict-free frag reads)
#define BSTRIDE 40     // 32 k + 8 pad

typedef __attribute__((ext_vector_type(8))) short bf16x8;
typedef __attribute__((ext_vector_type(4))) float f32x4;

static __device__ inline ushort f2bf_rne(float f) {
    union { float f; unsigned u; } c; c.f = f;
    unsigned u = c.u;
    unsigned r = (u + 0x7FFFu + ((u >> 16) & 1u)) >> 16;
    return (ushort)r;
}

__global__ __launch_bounds__(256, 2)
void binary_conv_kernel(const float* __restrict__ x, const float* __restrict__ w,
                        float* __restrict__ out)
{
    __shared__ __align__(16) ushort At[APIX * ASTRIDE]; // 48960 B
    __shared__ __align__(16) ushort Bt[128 * BSTRIDE];  // 10240 B

    const int tid = threadIdx.x;
    const int bx  = blockIdx.x;
    const int oc0 = blockIdx.y << 7;            // 0 or 128
    const int wt   = bx % 7;
    const int ht   = (bx / 7) % 14;
    const int nimg = bx / 98;
    const int h0 = ht * TH;
    const int w0 = wt * TW;

    // ---- Stage A once: 10x18 pixel tile with halo, all 128 ic, fp32 -> bf16 ----
    const float* xbase = x + (size_t)nimg * (112 * 112 * 128);
    for (int g = tid; g < APIX * 32; g += 256) {
        int pix = g >> 5;
        int ic  = (g & 31) << 2;                // float4 group
        int ph  = pix / PW;
        int pw  = pix - ph * PW;
        int hh  = h0 + ph - 1;
        int ww  = w0 + pw - 1;
        uint2 val; val.x = 0u; val.y = 0u;
        if ((unsigned)hh < 112u && (unsigned)ww < 112u) {
            const float4 v = *(const float4*)(xbase + ((size_t)(hh * 112 + ww) * 128 + ic));
            ushort b0 = f2bf_rne(v.x), b1 = f2bf_rne(v.y);
            ushort b2 = f2bf_rne(v.z), b3 = f2bf_rne(v.w);
            val.x = (unsigned)b0 | ((unsigned)b1 << 16);
            val.y = (unsigned)b2 | ((unsigned)b3 << 16);
        }
        *(uint2*)&At[pix * ASTRIDE + ic] = val;
    }

    const int wave = tid >> 6;
    const int lane = tid & 63;
    const int wm   = wave >> 1;   // 0..1: row quadrant
    const int wn   = wave & 1;    // 0..1: col quadrant
    const int l15  = lane & 15;
    const int quad = lane >> 4;   // 0..3

    f32x4 acc[4][4];
    for (int mt = 0; mt < 4; ++mt)
        for (int nt = 0; nt < 4; ++nt)
            acc[mt][nt] = (f32x4){0.f, 0.f, 0.f, 0.f};

    __syncthreads();   // A tile ready

    for (int kk = 0; kk < 36; ++kk) {
        const int kh  = kk / 12;
        const int kw_ = (kk >> 2) % 3;
        const int icc = kk & 3;

        // ---- Stage B chunk: w[kh][kw][icc*32 .. +31][oc0 .. +127], binarize,
        //      store transposed to Bt[n][k] so B-frags are contiguous in k ----
        __syncthreads();  // previous Bt fully consumed
        const float* wp = w + (size_t)(((kh * 3 + kw_) * 128 + (icc << 5)) * 256) + oc0;
        #pragma unroll
        for (int i = 0; i < 4; ++i) {
            int idx = i * 256 + tid;     // 0..1023
            int c   = idx & 127;         // oc within tile
            int k4  = idx >> 7;          // 0..7 : group of 4 k
            ushort b[4];
            #pragma unroll
            for (int j = 0; j < 4; ++j) {
                float v = wp[(size_t)((k4 * 4 + j) * 256) + c];
                b[j] = (v > 0.f) ? (ushort)0x3F80u : ((v < 0.f) ? (ushort)0xBF80u : (ushort)0u);
            }
            uint2 pv;
            pv.x = (unsigned)b[0] | ((unsigned)b[1] << 16);
            pv.y = (unsigned)b[2] | ((unsigned)b[3] << 16);
            *(uint2*)&Bt[c * BSTRIDE + (k4 << 2)] = pv;
        }
        __syncthreads();

        // ---- Fragments + MFMA ----
        bf16x8 af[4], bfr[4];
        const int pwl = l15 + kw_;
        const int icb = (icc << 5) + (quad << 3);
        #pragma unroll
        for (int mt = 0; mt < 4; ++mt) {
            int ph_ = wm * 4 + mt + kh;
            af[mt] = *(const bf16x8*)&At[(ph_ * PW + pwl) * ASTRIDE + icb];
        }
        const int kq = quad << 3;
        #pragma unroll
        for (int nt = 0; nt < 4; ++nt) {
            int nl = wn * 64 + nt * 16 + l15;
            bfr[nt] = *(const bf16x8*)&Bt[nl * BSTRIDE + kq];
        }
        #pragma unroll
        for (int mt = 0; mt < 4; ++mt)
            #pragma unroll
            for (int nt = 0; nt < 4; ++nt)
                acc[mt][nt] = __builtin_amdgcn_mfma_f32_16x16x32_bf16(
                    af[mt], bfr[nt], acc[mt][nt], 0, 0, 0);
    }

    // ---- Epilogue: C/D layout col=lane&15, row=quad*4+reg ----
    float* obase = out + ((size_t)nimg * 112 * 112) * 256 + oc0 + wn * 64 + l15;
    #pragma unroll
    for (int mt = 0; mt < 4; ++mt) {
        #pragma unroll
        for (int r = 0; r < 4; ++r) {
            int m  = wm * 64 + mt * 16 + quad * 4 + r;
            int dh = m >> 4;
            int dw = m & 15;
            float* orow = obase + (size_t)((h0 + dh) * 112 + (w0 + dw)) * 256;
            #pragma unroll
            for (int nt = 0; nt < 4; ++nt)
                orow[nt * 16] = acc[mt][nt][r];
        }
    }
}

extern "C" void kernel_launch(void* const* d_in, const int* in_sizes, int n_in,
                              void* d_out, int out_size, void* d_ws, size_t ws_size,
                              hipStream_t stream) {
    const float* x = (const float*)d_in[0];
    const float* w = (const float*)d_in[1];
    float* out = (float*)d_out;
    dim3 grid(32 * 14 * 7, 2);
    dim3 block(256);
    hipLaunchKernelGGL(binary_conv_kernel, grid, block, 0, stream, x, w, out);
}

// Round 2
// 835.287 us; speedup vs baseline: 1.2550x; 1.2550x over previous
//
#include <hip/hip_runtime.h>
#include <hip/hip_bf16.h>

// Binary conv: out = conv2d(x, sign(w)), SAME, stride 1, NHWC.
// x: (32,112,112,128) f32, w: (3,3,128,256) f32, out: (32,112,112,256) f32.
//
// Round 2: prep kernel binarizes+packs w -> bf16 in LDS-image order (XOR
// swizzled), main kernel stages B chunks with async global_load_lds (16B),
// double-buffered, 1 barrier per 32 MFMAs.

#define TH 8
#define TW 16
#define PH 10          // TH + 2 halo
#define PW 18          // TW + 2 halo
#define APIX (PH * PW) // 180 pixels
#define ASTRIDE 136    // 128 ic + 8 pad (keeps 16B alignment: 136*2=272=16*17)

typedef __attribute__((ext_vector_type(8))) short bf16x8;
typedef __attribute__((ext_vector_type(4))) float f32x4;

static __device__ inline ushort f2bf_rne(float f) {
    union { float f; unsigned u; } c; c.f = f;
    unsigned u = c.u;
    unsigned r = (u + 0x7FFFu + ((u >> 16) & 1u)) >> 16;
    return (ushort)r;
}

// ---- Prep: pack sign(w) into bf16, layout = [t(oc half)][c(18 K-chunks of 64)]
//      [n 0..127][g_phys 0..7][8 bf16], with g_phys = g_log ^ (n&7).
//      K order: k = (kh*3+kw)*128 + ic; chunk c covers k in [64c, 64c+64):
//      kh=c/6, kw=(c%6)>>1, h=c&1, ic = h*64 + g_log*8 + j.
__global__ void pack_w_kernel(const float* __restrict__ w, ushort* __restrict__ wp) {
    int u = blockIdx.x * 256 + threadIdx.x;   // 0 .. 36863
    int n  = u & 127;
    int v  = u >> 7;
    int g  = v & 7;           // g_log
    int tc = v >> 3;          // t*18 + c
    int c  = tc % 18;
    int kh = c / 6;
    int r6 = c % 6;
    int kw = r6 >> 1;
    int h  = r6 & 1;
    int t  = tc / 18;
    int icb = h * 64 + g * 8;
    const float* src = w + (size_t)((kh * 3 + kw) * 128 + icb) * 256 + t * 128 + n;
    ushort b[8];
    #pragma unroll
    for (int j = 0; j < 8; ++j) {
        float vv = src[(size_t)j * 256];
        b[j] = (vv > 0.f) ? (ushort)0x3F80u : ((vv < 0.f) ? (ushort)0xBF80u : (ushort)0u);
    }
    int gp = g ^ (n & 7);
    uint4 pv;
    pv.x = (unsigned)b[0] | ((unsigned)b[1] << 16);
    pv.y = (unsigned)b[2] | ((unsigned)b[3] << 16);
    pv.z = (unsigned)b[4] | ((unsigned)b[5] << 16);
    pv.w = (unsigned)b[6] | ((unsigned)b[7] << 16);
    *(uint4*)(wp + ((size_t)(tc * 128 + n) * 8 + gp) * 8) = pv;
}

__global__ __launch_bounds__(256, 2)
void binary_conv_kernel(const float* __restrict__ x, const ushort* __restrict__ wp,
                        float* __restrict__ out)
{
    __shared__ __align__(16) ushort At[APIX * ASTRIDE];  // 48960 B
    __shared__ __align__(16) ushort Bt[2 * 128 * 64];    // 32768 B, double-buffered

    const int tid = threadIdx.x;
    const int bx  = blockIdx.x;
    const int oc0 = blockIdx.y << 7;
    const int wt   = bx % 7;
    const int ht   = (bx / 7) % 14;
    const int nimg = bx / 98;
    const int h0 = ht * TH;
    const int w0 = wt * TW;

    // B source for this oc half: 18 chunks x 8192 elements
    const ushort* wsrc = wp + (size_t)blockIdx.y * 18 * 8192;
    const int wave = tid >> 6;

    // Issue one 16KB B chunk (4 async 16B issues/thread)
    auto issueB = [&](int c, int buf) {
        const ushort* s = wsrc + c * 8192 + tid * 8;
        ushort* l = Bt + buf * 8192 + wave * 512;
        #pragma unroll
        for (int i = 0; i < 4; ++i) {
            __builtin_amdgcn_global_load_lds(
                (const __attribute__((address_space(1))) void*)(s + i * 2048),
                (__attribute__((address_space(3))) void*)(l + i * 2048),
                16, 0, 0);
        }
    };

    // Prefetch B chunk 0 before A staging (independent)
    issueB(0, 0);

    // ---- Stage A once: 10x18 pixel tile with halo, 128 ic, fp32 -> bf16 ----
    const float* xbase = x + (size_t)nimg * (112 * 112 * 128);
    for (int g = tid; g < APIX * 32; g += 256) {
        int pix = g >> 5;
        int ic  = (g & 31) << 2;
        int ph  = pix / PW;
        int pw  = pix - ph * PW;
        int hh  = h0 + ph - 1;
        int ww  = w0 + pw - 1;
        uint2 val; val.x = 0u; val.y = 0u;
        if ((unsigned)hh < 112u && (unsigned)ww < 112u) {
            const float4 v = *(const float4*)(xbase + ((size_t)(hh * 112 + ww) * 128 + ic));
            val.x = (unsigned)f2bf_rne(v.x) | ((unsigned)f2bf_rne(v.y) << 16);
            val.y = (unsigned)f2bf_rne(v.z) | ((unsigned)f2bf_rne(v.w) << 16);
        }
        *(uint2*)&At[pix * ASTRIDE + ic] = val;
    }

    const int lane = tid & 63;
    const int wm   = wave >> 1;
    const int wn   = wave & 1;
    const int l15  = lane & 15;
    const int quad = lane >> 4;

    f32x4 acc[4][4];
    #pragma unroll
    for (int mt = 0; mt < 4; ++mt)
        #pragma unroll
        for (int nt = 0; nt < 4; ++nt)
            acc[mt][nt] = (f32x4){0.f, 0.f, 0.f, 0.f};

    __syncthreads();   // A tile + B chunk 0 ready (barrier drains vmcnt)

    for (int c = 0; c < 18; ++c) {
        if (c < 17) issueB(c + 1, (c + 1) & 1);   // prefetch hides behind MFMAs

        const int kh  = c / 6;
        const int r6  = c % 6;
        const int kwv = r6 >> 1;
        const int hlf = r6 & 1;
        const ushort* bbase = Bt + (c & 1) * 8192;

        #pragma unroll
        for (int p = 0; p < 2; ++p) {
            const int ico = hlf * 64 + p * 32 + (quad << 3);
            bf16x8 af[4], bfr[4];
            #pragma unroll
            for (int mt = 0; mt < 4; ++mt) {
                int ph_ = wm * 4 + mt + kh;
                af[mt] = *(const bf16x8*)&At[(ph_ * PW + l15 + kwv) * ASTRIDE + ico];
            }
            #pragma unroll
            for (int nt = 0; nt < 4; ++nt) {
                int nl = wn * 64 + nt * 16 + l15;
                int gph = (p * 4 + quad) ^ (nl & 7);
                bfr[nt] = *(const bf16x8*)&bbase[nl * 64 + gph * 8];
            }
            #pragma unroll
            for (int mt = 0; mt < 4; ++mt)
                #pragma unroll
                for (int nt = 0; nt < 4; ++nt)
                    acc[mt][nt] = __builtin_amdgcn_mfma_f32_16x16x32_bf16(
                        af[mt], bfr[nt], acc[mt][nt], 0, 0, 0);
        }
        __syncthreads();  // drains prefetch c+1; guards buf reuse at c+2
    }

    // ---- Epilogue: C/D layout col=lane&15, row=quad*4+reg ----
    float* obase = out + ((size_t)nimg * 112 * 112) * 256 + oc0 + wn * 64 + l15;
    #pragma unroll
    for (int mt = 0; mt < 4; ++mt) {
        #pragma unroll
        for (int r = 0; r < 4; ++r) {
            int m  = wm * 64 + mt * 16 + quad * 4 + r;
            int dh = m >> 4;
            int dw = m & 15;
            float* orow = obase + (size_t)((h0 + dh) * 112 + (w0 + dw)) * 256;
            #pragma unroll
            for (int nt = 0; nt < 4; ++nt)
                orow[nt * 16] = acc[mt][nt][r];
        }
    }
}

extern "C" void kernel_launch(void* const* d_in, const int* in_sizes, int n_in,
                              void* d_out, int out_size, void* d_ws, size_t ws_size,
                              hipStream_t stream) {
    const float* x = (const float*)d_in[0];
    const float* w = (const float*)d_in[1];
    float* out = (float*)d_out;
    ushort* wpack = (ushort*)d_ws;   // 589824 B

    hipLaunchKernelGGL(pack_w_kernel, dim3(144), dim3(256), 0, stream, w, wpack);

    dim3 grid(32 * 14 * 7, 2);
    hipLaunchKernelGGL(binary_conv_kernel, grid, dim3(256), 0, stream, x, wpack, out);
}